// Round 3
// baseline (1032.198 us; speedup 1.0000x reference)
//
#include <hip/hip_runtime.h>

// ---------------------------------------------------------------------------
// GlobalMetaAggregator  R=2,K=3,N=16384,V=256,E=1,L=8,VE=128,LK=1,OUT=64,
// IN=256,HID=512,C=5.
// Round 8: mgemm K-loop -> counted-vmcnt pipeline (T4): triple-buffered LDS,
// depth-2 prefetch, ONE raw s_barrier per K-step, per-wave lgkmcnt(0) drain
// before the barrier (WAR safety), s_waitcnt vmcnt(S) counted waits (never 0
// in steady state) so global_load_lds stays in flight across barriers.
// Theory: __syncthreads' vmcnt(0) drain per step was the serializer.
// ---------------------------------------------------------------------------

typedef unsigned short bf16_t;
using ushort8v = __attribute__((ext_vector_type(8))) unsigned short;
using bf16x8   = __attribute__((ext_vector_type(8))) __bf16;
using f32x4    = __attribute__((ext_vector_type(4))) float;

#define WAITV(N) asm volatile("s_waitcnt vmcnt(%0)" :: "n"(N) : "memory")
#define WAITL0() asm volatile("s_waitcnt lgkmcnt(0)" ::: "memory")

__device__ __forceinline__ float bf2f(bf16_t u) {
    return __uint_as_float(((unsigned int)u) << 16);
}
__device__ __forceinline__ bf16_t f2bf(float f) {
    unsigned int u = __float_as_uint(f);
    u += 0x7FFFu + ((u >> 16) & 1u);   // RNE
    return (bf16_t)(u >> 16);
}
__device__ __forceinline__ float ld1(const void* p, long i, int dt) {
    return dt ? bf2f(((const bf16_t*)p)[i]) : ((const float*)p)[i];
}
__device__ __forceinline__ float4 ld4(const void* p, long i, int dt) {
    if (dt) {
        ushort4 v = *(const ushort4*)((const bf16_t*)p + i);
        return make_float4(bf2f(v.x), bf2f(v.y), bf2f(v.z), bf2f(v.w));
    }
    return *(const float4*)((const float*)p + i);
}
__device__ __forceinline__ ushort8v ld8bf(const void* p, long i, int dt) {
    if (dt) return *(const ushort8v*)((const bf16_t*)p + i);
    const float* f = (const float*)p + i;
    float4 a = *(const float4*)f, b = *(const float4*)(f + 4);
    ushort8v r;
    r[0] = f2bf(a.x); r[1] = f2bf(a.y); r[2] = f2bf(a.z); r[3] = f2bf(a.w);
    r[4] = f2bf(b.x); r[5] = f2bf(b.y); r[6] = f2bf(b.z); r[7] = f2bf(b.w);
    return r;
}
__device__ __forceinline__ float decode_scalar(const void* p, int isbf) {
    if (!isbf) return *(const float*)p;
    unsigned int u = *(const unsigned int*)p;
    if ((u & 0xFFFFu) == 0u) return __uint_as_float(u);
    return bf2f((bf16_t)(u & 0xFFFFu));
}
__device__ __forceinline__ float wave_reduce(float v) {
#pragma unroll
    for (int o = 32; o > 0; o >>= 1) v += __shfl_down(v, o, 64);
    return v;
}
// direct global -> LDS copy, 16 bytes per lane. LDS dest must be
// wave-uniform; hardware writes lane l's data at ldsbase + l*16.
__device__ __forceinline__ void gl_lds16(const void* g, void* l) {
    __builtin_amdgcn_global_load_lds(
        (const __attribute__((address_space(1))) void*)g,
        (__attribute__((address_space(3))) void*)l, 16, 0, 0);
}

// ---------------------------------------------------------------------------
__global__ void detect_k(const unsigned int* __restrict__ w, long nwords,
                         int* __restrict__ flag)
{
    const int lane = threadIdx.x;
    long idx = (long)lane * 997 + 13;
    if (idx >= nwords) idx = lane % (nwords > 0 ? nwords : 1);
    unsigned int word = w[idx];
    int e = (word >> 7) & 0xFF;
    int vote = (e >= 110 && e <= 134) ? 1 : 0;
    unsigned long long m = __ballot(vote);
    if (lane == 0) *flag = (__popcll(m) >= 32) ? 1 : 0;
}

// ---------------------------------------------------------------------------
// transpose: in [K][N] (flag dtype) -> out [N][K] bf16, batched over z
// ---------------------------------------------------------------------------
__global__ __launch_bounds__(256) void transT_k(
    const void* __restrict__ in, long inoff, long sInZ, int Kd, int Nd,
    bf16_t* __restrict__ out, long outoff, long sOutZ,
    const int* __restrict__ flag)
{
    const int isbf = *flag;
    const long z = blockIdx.z;
    long idx = (long)blockIdx.x * 256 + threadIdx.x;
    if (idx >= (long)Kd * Nd) return;
    int k = (int)(idx / Nd), n = (int)(idx % Nd);
    out[outoff + z * sOutZ + (long)n * Kd + k] =
        f2bf(ld1(in, inoff + z * sInZ + idx, isbf));
}

// ---------------------------------------------------------------------------
// fold GEMM (small): CT = (A@B)^T bf16.  A [M][K], B [K][N] flag dtype.
// ---------------------------------------------------------------------------
__global__ __launch_bounds__(256) void fold_gemmT_k(
    const void* __restrict__ A, long aoff, long sAz, int lda,
    const void* __restrict__ B, long boff, long sBz, int ldb,
    bf16_t* __restrict__ CT, long coff, long sCz, int ldcT,
    int K, const int* __restrict__ flag)
{
    const int isbf = *flag;
    __shared__ __align__(16) float As[16][68];
    __shared__ __align__(16) float Bs[16][68];
    const int z = blockIdx.z, t = threadIdx.x;
    const int tx = t & 15, ty = t >> 4;
    const int am = t >> 2, ak = (t & 3) << 2;
    const int bn = tx << 2;
    const long aBase = aoff + z * sAz + (long)(blockIdx.y * 64 + am) * lda + ak;
    const long bBase = boff + z * sBz + (long)ty * ldb + blockIdx.x * 64 + bn;
    float acc[4][4] = {};
    for (int k0 = 0; k0 < K; k0 += 16) {
        float4 av = ld4(A, aBase + k0, isbf);
        float4 bv = ld4(B, bBase + (long)k0 * ldb, isbf);
        __syncthreads();
        As[ak + 0][am] = av.x; As[ak + 1][am] = av.y;
        As[ak + 2][am] = av.z; As[ak + 3][am] = av.w;
        *(float4*)&Bs[ty][bn] = bv;
        __syncthreads();
#pragma unroll
        for (int k = 0; k < 16; k++) {
            float4 a4 = *(const float4*)&As[k][ty << 2];
            float4 b4 = *(const float4*)&Bs[k][tx << 2];
            float ar[4] = {a4.x, a4.y, a4.z, a4.w};
            float br[4] = {b4.x, b4.y, b4.z, b4.w};
#pragma unroll
            for (int i = 0; i < 4; i++)
#pragma unroll
                for (int j = 0; j < 4; j++) acc[i][j] += ar[i] * br[j];
        }
    }
    const int cm = blockIdx.y * 64 + (ty << 2);
    const int cn = blockIdx.x * 64 + (tx << 2);
#pragma unroll
    for (int i = 0; i < 4; i++)
#pragma unroll
        for (int j = 0; j < 4; j++)
            CT[coff + z * sCz + (long)(cn + j) * ldcT + (cm + i)] = f2bf(acc[i][j]);
}

// ---------------------------------------------------------------------------
// MFMA GEMM: C[z] = A[z] @ BT[z]^T (+bias)(+PReLU), f32 accumulate.
// Per-z offsets: with zq=z/zdiv, zr=z%zdiv, offset = off + zq*s1 + zr*s2.
// A [M][K] (adt 0=f32,1=bf16,2=flag), BT [N][K] bf16.
// Tile 128 x BN_, BK=32, 4 waves (2x2), wave tile 64 x WNW_.
// MODE: 0 none, 1 +bias, 2 +bias+PReLU.  CD: 1 bf16 out, 2 flag-dtype out.
// Counted-vmcnt pipeline: 3 LDS buffers, depth-2 prefetch, 1 barrier/step.
// Per iter ti: lgkmcnt(0) [my reads of buf[ti-1] done -> WAR safe];
// vmcnt(S) [tile ti landed, tile ti+1 in flight]; s_barrier;
// STAGE(ti+2 -> buf[(ti+2)%3]); ds_read buf[ti%3]; MFMA.
// ---------------------------------------------------------------------------
template <int BN_, int WNW_, int MODE, int CD>
__global__ __launch_bounds__(256) void mgemm(
    const void* __restrict__ A, int adt, long aoff, long sA1, long sA2, int lda,
    const bf16_t* __restrict__ BT, long boff, long sB1, long sB2,
    void* __restrict__ C, long coff, long sC1, long sC2, int ldc,
    const void* __restrict__ bias, long biasoff, long sBi1, long sBi2,
    const void* __restrict__ alpha_ptr, int K, int zdiv,
    const int* __restrict__ flag)
{
    constexpr int NJ = WNW_ / 16;
    constexpr int BROUNDS = BN_ / 64;   // 256 lanes * 16B = 64 rows per round
    const int isbf = *flag;
    const int adt_ = (adt == 2) ? isbf : adt;
    const int cdt = (CD == 2) ? isbf : 1;

    __shared__ __align__(16) unsigned short As[3][128 * 32];
    __shared__ __align__(16) unsigned short Bs[3][BN_ * 32];

    const int t = threadIdx.x;
    const int lane = t & 63, w = t >> 6;
    const int quad = lane >> 4, r16 = lane & 15;
    const int wy = w >> 1, wx = w & 1;
    const int z = blockIdx.z;
    const int zq = z / zdiv, zr = z % zdiv;
    const long blockM = (long)blockIdx.y * 128;
    const int  blockN = blockIdx.x * BN_;

    f32x4 acc[4][NJ];
    const f32x4 zero4 = {0.f, 0.f, 0.f, 0.f};
#pragma unroll
    for (int i = 0; i < 4; i++)
#pragma unroll
        for (int j = 0; j < NJ; j++) acc[i][j] = zero4;

    const long aBase = aoff + zq * sA1 + zr * sA2;
    const long bBase = boff + zq * sB1 + zr * sB2;

    const bool fastA = (adt_ == 1);
    const bf16_t* Abf = (const bf16_t*)A;

    // stage one BK=32 K-tile into buffer `buf`
    auto STAGE = [&](int buf, int ti) {
        const int k0 = ti << 5;
        if (fastA) {
#pragma unroll
            for (int c = 0; c < 2; c++) {
                const int lin = c * 256 + t;             // lin = m*4 + k8
                const int m = lin >> 2, kq = (lin & 3) * 8;
                gl_lds16(Abf + aBase + (blockM + m) * (long)lda + k0 + kq,
                         &As[buf][(size_t)(c * 256 + w * 64) * 8]);
            }
        } else {
            ushort8v av[2];
#pragma unroll
            for (int c = 0; c < 2; c++) {
                const int lin = c * 256 + t;
                const int m = lin >> 2, kq = (lin & 3) * 8;
                av[c] = ld8bf(A, aBase + (blockM + m) * (long)lda + k0 + kq, 0);
            }
#pragma unroll
            for (int c = 0; c < 2; c++)
                *(ushort8v*)&As[buf][(size_t)(c * 256 + t) * 8] = av[c];
        }
#pragma unroll
        for (int c = 0; c < BROUNDS; c++) {
            const int lin = c * 256 + t;
            const int n = lin >> 2, kq = (lin & 3) * 8;
            gl_lds16(BT + bBase + (long)(blockN + n) * K + k0 + kq,
                     &Bs[buf][(size_t)(c * 256 + w * 64) * 8]);
        }
    };

    const int nt = K >> 5;
    STAGE(0, 0);
    if (nt > 1) STAGE(1, 1);

    int cur = 0;
    for (int ti = 0; ti < nt; ++ti) {
        // WAR safety: my ds_reads (and any staged ds_writes) complete
        WAITL0();
        // tile ti landed; tile ti+1 (if staged) may remain in flight
        if (fastA) {
            if (ti + 1 < nt) WAITV(2 + BROUNDS); else WAITV(0);
        } else {
            if (ti + 1 < nt) WAITV(BROUNDS);     else WAITV(0);
        }
        __builtin_amdgcn_s_barrier();
        __builtin_amdgcn_sched_barrier(0);

        // depth-2 prefetch into the buffer last read at iter ti-1
        if (ti + 2 < nt) {
            int sb = cur + 2; if (sb >= 3) sb -= 3;
            STAGE(sb, ti + 2);
        }

        bf16x8 af[4], bfr[NJ];
#pragma unroll
        for (int i = 0; i < 4; i++) {
            int m = wy * 64 + i * 16 + r16;
            af[i] = __builtin_bit_cast(bf16x8,
                        *(const ushort8v*)&As[cur][m * 32 + quad * 8]);
        }
#pragma unroll
        for (int j = 0; j < NJ; j++) {
            int n = wx * WNW_ + j * 16 + r16;
            bfr[j] = __builtin_bit_cast(bf16x8,
                        *(const ushort8v*)&Bs[cur][n * 32 + quad * 8]);
        }
#pragma unroll
        for (int i = 0; i < 4; i++)
#pragma unroll
            for (int j = 0; j < NJ; j++)
                acc[i][j] = __builtin_amdgcn_mfma_f32_16x16x32_bf16(
                    af[i], bfr[j], acc[i][j], 0, 0, 0);

        cur = (cur == 2) ? 0 : cur + 1;
    }

    const float alpha = (MODE == 2) ? decode_scalar(alpha_ptr, isbf) : 0.f;
    const long cBase = coff + zq * sC1 + zr * sC2;
#pragma unroll
    for (int j = 0; j < NJ; j++) {
        const int n = blockN + wx * WNW_ + j * 16 + r16;
        const float bz = (MODE >= 1)
            ? ld1(bias, biasoff + zq * sBi1 + zr * sBi2 + n, isbf) : 0.f;
#pragma unroll
        for (int i = 0; i < 4; i++) {
            const long m0 = blockM + wy * 64 + i * 16 + quad * 4;
#pragma unroll
            for (int rg = 0; rg < 4; rg++) {
                float v = acc[i][j][rg] + bz;
                if (MODE == 2) v = (v >= 0.f) ? v : alpha * v;
                const long off = cBase + (m0 + rg) * (long)ldc + n;
                if (cdt) ((bf16_t*)C)[off] = f2bf(v);
                else     ((float*)C)[off] = v;
            }
        }
    }
}

// ---------------------------------------------------------------------------
// extra pool: ME bf16 [2][Nc*8,256]; sigmoid-softmax over L=8 -> EO f32
// grid (Nc, 2)
// ---------------------------------------------------------------------------
__global__ __launch_bounds__(256) void pool_extra_k(
    const bf16_t* __restrict__ ME, long sMEz, const void* __restrict__ wx,
    float* __restrict__ EO, long sEOz, const int* __restrict__ flag)
{
    const int isbf = *flag;
    const int n = blockIdx.x, t = threadIdx.x;
    const bf16_t* base = ME + blockIdx.y * sMEz + (long)n * 2048;
    float v[8];
#pragma unroll
    for (int l = 0; l < 8; l++) v[l] = bf2f(base[l * 256 + t]);
    const float w = ld1(wx, t, isbf);
    __shared__ float red[8][4];
    const int lane = t & 63, wid = t >> 6;
#pragma unroll
    for (int l = 0; l < 8; l++) {
        float pr = wave_reduce(v[l] * w);
        if (lane == 0) red[l][wid] = pr;
    }
    __syncthreads();
    float gv[8], ssum = 0.f;
#pragma unroll
    for (int l = 0; l < 8; l++) {
        float sc = red[l][0] + red[l][1] + red[l][2] + red[l][3];
        float sg = 1.f / (1.f + expf(-sc));
        float e = expf(sg);
        gv[l] = e; ssum += e;
    }
    const float inv = 1.f / ssum;
    float o = 0.f;
#pragma unroll
    for (int l = 0; l < 8; l++) o += gv[l] * inv * v[l];
    EO[blockIdx.y * sEOz + (long)n * 256 + t] = o;
}

// ---------------------------------------------------------------------------
// LN over (5,512)=2560 + PReLU, in place, bf16; grid = #rows
// ---------------------------------------------------------------------------
__global__ __launch_bounds__(256) void ln1_k(
    bf16_t* __restrict__ X, const void* __restrict__ g,
    const void* __restrict__ be, const void* __restrict__ alpha_ptr,
    const int* __restrict__ flag)
{
    const int isbf = *flag;
    const int n = blockIdx.x, t = threadIdx.x;
    bf16_t* row = X + (long)n * 2560;
    float v[10], s = 0.f, sq = 0.f;
#pragma unroll
    for (int i = 0; i < 10; i++) {
        float x = bf2f(row[i * 256 + t]);
        v[i] = x; s += x; sq += x * x;
    }
    __shared__ float redS[4], redQ[4];
    const int lane = t & 63, wid = t >> 6;
    float ws_ = wave_reduce(s), wq = wave_reduce(sq);
    if (lane == 0) { redS[wid] = ws_; redQ[wid] = wq; }
    __syncthreads();
    const float S = redS[0] + redS[1] + redS[2] + redS[3];
    const float Q = redQ[0] + redQ[1] + redQ[2] + redQ[3];
    const float mean = S * (1.f / 2560.f);
    const float rstd = rsqrtf(fmaxf(Q * (1.f / 2560.f) - mean * mean, 0.f) + 1e-5f);
    const float alpha = decode_scalar(alpha_ptr, isbf);
#pragma unroll
    for (int i = 0; i < 10; i++) {
        int e = i * 256 + t;
        float y = (v[i] - mean) * rstd * ld1(g, e, isbf) + ld1(be, e, isbf);
        row[e] = f2bf((y >= 0.f) ? y : alpha * y);
    }
}

// ---------------------------------------------------------------------------
// LN2 + PReLU + channel pool (C=5) -> H[n*1024 + r*512 + :] bf16
// grid (Nc, 2): blockIdx.y = relation
// ---------------------------------------------------------------------------
__global__ __launch_bounds__(256) void ln2_pool_k(
    const bf16_t* __restrict__ X, long sXz, const void* __restrict__ g,
    const void* __restrict__ be, const void* __restrict__ alpha_ptr,
    const void* __restrict__ wr,
    bf16_t* __restrict__ H, const int* __restrict__ flag)
{
    const int isbf = *flag;
    const int n = blockIdx.x, t = threadIdx.x, rr = blockIdx.y;
    const bf16_t* row = X + rr * sXz + (long)n * 2560;
    float v[5][2], s = 0.f, sq = 0.f;
#pragma unroll
    for (int c = 0; c < 5; c++)
#pragma unroll
        for (int hi = 0; hi < 2; hi++) {
            float x = bf2f(row[c * 512 + hi * 256 + t]);
            v[c][hi] = x; s += x; sq += x * x;
        }
    __shared__ float redS[4], redQ[4];
    const int lane = t & 63, wid = t >> 6;
    float ws_ = wave_reduce(s), wq = wave_reduce(sq);
    if (lane == 0) { redS[wid] = ws_; redQ[wid] = wq; }
    __syncthreads();
    const float S = redS[0] + redS[1] + redS[2] + redS[3];
    const float Q = redQ[0] + redQ[1] + redQ[2] + redQ[3];
    const float mean = S * (1.f / 2560.f);
    const float rstd = rsqrtf(fmaxf(Q * (1.f / 2560.f) - mean * mean, 0.f) + 1e-5f);
    const float alpha = decode_scalar(alpha_ptr, isbf);
    const float w0 = ld1(wr, (long)rr * 512 + t, isbf);
    const float w1 = ld1(wr, (long)rr * 512 + t + 256, isbf);
    float p[5];
#pragma unroll
    for (int c = 0; c < 5; c++) {
        p[c] = 0.f;
#pragma unroll
        for (int hi = 0; hi < 2; hi++) {
            int e = c * 512 + hi * 256 + t;
            float y = (v[c][hi] - mean) * rstd * ld1(g, e, isbf) + ld1(be, e, isbf);
            y = (y >= 0.f) ? y : alpha * y;
            v[c][hi] = y;
            p[c] += y * (hi ? w1 : w0);
        }
    }
    __shared__ float redP[5][4];
#pragma unroll
    for (int c = 0; c < 5; c++) {
        float pr = wave_reduce(p[c]);
        if (lane == 0) redP[c][wid] = pr;
    }
    __syncthreads();
    float gv[5], ssum = 0.f;
#pragma unroll
    for (int c = 0; c < 5; c++) {
        float sc = redP[c][0] + redP[c][1] + redP[c][2] + redP[c][3];
        float sg = 1.f / (1.f + expf(-sc));
        float e = expf(sg);
        gv[c] = e; ssum += e;
    }
    const float inv = 1.f / ssum;
#pragma unroll
    for (int hi = 0; hi < 2; hi++) {
        float o = 0.f;
#pragma unroll
        for (int c = 0; c < 5; c++) o += gv[c] * inv * v[c][hi];
        H[(long)n * 1024 + rr * 512 + hi * 256 + t] = f2bf(o);
    }
}

// ---------------------------------------------------------------------------
// global pool over R=2: H[Nc,2,512] -> F[Nc,512] bf16
// ---------------------------------------------------------------------------
__global__ __launch_bounds__(256) void gpool_k(
    const bf16_t* __restrict__ H, const void* __restrict__ wg,
    bf16_t* __restrict__ F, const int* __restrict__ flag)
{
    const int isbf = *flag;
    const int n = blockIdx.x, t = threadIdx.x;
    const bf16_t* base = H + (long)n * 1024;
    const float w0 = ld1(wg, t, isbf), w1 = ld1(wg, t + 256, isbf);
    float v[2][2], p[2];
#pragma unroll
    for (int r = 0; r < 2; r++) {
        v[r][0] = bf2f(base[r * 512 + t]);
        v[r][1] = bf2f(base[r * 512 + 256 + t]);
        p[r] = v[r][0] * w0 + v[r][1] * w1;
    }
    __shared__ float red[2][4];
    const int lane = t & 63, wid = t >> 6;
#pragma unroll
    for (int r = 0; r < 2; r++) {
        float pr = wave_reduce(p[r]);
        if (lane == 0) red[r][wid] = pr;
    }
    __syncthreads();
    float gv[2], ssum = 0.f;
#pragma unroll
    for (int r = 0; r < 2; r++) {
        float sc = red[r][0] + red[r][1] + red[r][2] + red[r][3];
        float sg = 1.f / (1.f + expf(-sc));
        float e = expf(sg);
        gv[r] = e; ssum += e;
    }
    const float inv = 1.f / ssum;
#pragma unroll
    for (int hi = 0; hi < 2; hi++) {
        F[(long)n * 512 + hi * 256 + t] =
            f2bf((gv[0] * v[0][hi] + gv[1] * v[1][hi]) * inv);
    }
}

// ---------------------------------------------------------------------------
extern "C" void kernel_launch(void* const* d_in, const int* in_sizes, int n_in,
                              void* d_out, int out_size, void* d_ws, size_t ws_size,
                              hipStream_t stream)
{
    const void* raw   = d_in[0];   // (2,3,16384,256)
    const void* extra = d_in[1];   // (2,1,16384,8,128)
    const void* lbl   = d_in[2];   // (2,1,16384,64)
    const void* femb  = d_in[3];   // (2,3,256,256)
    const void* eemb  = d_in[4];   // (2,1,128,256)
    const void* lemb  = d_in[5];   // (2,1,64,256)
    const void* wx    = d_in[6];   // (1,256)
    const void* wr    = d_in[7];   // (2,512)
    const void* wg    = d_in[8];   // (512,)
    const void* W1    = d_in[9];   // (5,256,512)
    const void* b1    = d_in[10];  // (5,512)
    const void* g1    = d_in[11];
    const void* be1   = d_in[12];
    const void* a1    = d_in[13];
    const void* W2    = d_in[14];  // (5,512,512)
    const void* b2    = d_in[15];
    const void* g2    = d_in[16];
    const void* be2   = d_in[17];
    const void* a2    = d_in[18];
    const void* Wf1   = d_in[19];  // (512,512)
    const void* bf1   = d_in[20];
    const void* af    = d_in[21];
    const void* Wf2   = d_in[22];  // (512,64)
    const void* bf2b  = d_in[23];

    // ---- workspace: flag | transposed bf16 weights | arena ----
    int*    flag  = (int*)d_ws;
    bf16_t* MfT   = (bf16_t*)((char*)d_ws + 256);  // [2][3][512][256]
    bf16_t* MlT   = MfT + 786432;                  // [2][512][64]
    bf16_t* W1c3T = MlT + 65536;                   // [512][256]
    bf16_t* W2T   = W1c3T + 131072;                // [5][512][512]
    bf16_t* Wf1T  = W2T + 1310720;                 // [512][512]
    bf16_t* Wf2T  = Wf1T + 262144;                 // [64][512]
    bf16_t* eT    = Wf2T + 32768;                  // [2][256][128]
    char*   arena = (char*)(eT + 65536);
    const size_t fixedBytes = 256 + 2654208 * 2;

    // per-node arena bytes: x1 2*5120 + x2 2*5120 + eoc 2*1024 + hbc 2048
    int Nc = 16384;
    while (Nc > 128 && fixedBytes + (size_t)Nc * 24576 > ws_size) Nc >>= 1;
    const int NCH = 16384 / Nc;

    bf16_t* x1  = (bf16_t*)arena;                           // [2][Nc][2560]
    bf16_t* x2  = (bf16_t*)(arena + (size_t)Nc * 10240);    // [2][Nc][2560]
    float*  eo  = (float*) (arena + (size_t)Nc * 20480);    // [2][Nc][256] f32
    bf16_t* hbc = (bf16_t*)(arena + (size_t)Nc * 22528);    // [Nc][2][512]
    bf16_t* mec = x1;                                       // [2][Nc*8][256] alias (8192B/node <= 10240)
    bf16_t* fin = x2;                                       // [Nc][512] alias
    bf16_t* zb  = x2 + (size_t)Nc * 512;                    // [Nc][512] alias

    dim3 blk(256);

    detect_k<<<1, 64, 0, stream>>>((const unsigned int*)raw,
                                   (long)in_sizes[0] / 2, flag);

    // ---- weight transposes (bf16 [N][K]) ----
    transT_k<<<dim3(1024, 1, 5), blk, 0, stream>>>(W2, 0, 262144, 512, 512,
                                                   W2T, 0, 262144, flag);
    transT_k<<<dim3(512, 1, 1), blk, 0, stream>>>(W1, 3L * 131072, 0, 256, 512,
                                                  W1c3T, 0, 0, flag);
    transT_k<<<dim3(1024, 1, 1), blk, 0, stream>>>(Wf1, 0, 0, 512, 512,
                                                   Wf1T, 0, 0, flag);
    transT_k<<<dim3(128, 1, 1), blk, 0, stream>>>(Wf2, 0, 0, 512, 64,
                                                  Wf2T, 0, 0, flag);
    transT_k<<<dim3(128, 1, 2), blk, 0, stream>>>(eemb, 0, 32768, 128, 256,
                                                  eT, 0, 32768, flag);

    // ---- folds: MfT[r,k] = (femb[r,k]@W1[k])^T, MlT[r] = (lemb[r]@W1[4])^T
    for (int r = 0; r < 2; r++) {
        fold_gemmT_k<<<dim3(8, 4, 3), blk, 0, stream>>>(
            femb, (long)r * 196608, 65536, 256,
            W1, 0, 131072, 512,
            MfT, (long)r * 393216, 131072, 256, 256, flag);
    }
    fold_gemmT_k<<<dim3(8, 1, 2), blk, 0, stream>>>(
        lemb, 0, 16384, 256,
        W1, 4L * 131072, 0, 512,
        MlT, 0, 32768, 64, 256, flag);

    for (int c = 0; c < NCH; c++) {
        const long n0 = (long)c * Nc;

        // me[r] = extra[r,chunk] [Nc*8,128] @ eT[r]^T -> mec [2][Nc*8][256]
        mgemm<128, 64, 0, 1><<<dim3(2, Nc * 8 / 128, 2), blk, 0, stream>>>(
            extra, 2, n0 * 1024, 16777216, 0, 128,
            eT, 0, 32768, 0,
            mec, 0, (long)Nc * 8 * 256, 0, 256,
            nullptr, 0, 0, 0, nullptr, 128, 1, flag);
        // pool over L=8 -> eo[2][Nc][256]
        pool_extra_k<<<dim3(Nc, 2), blk, 0, stream>>>(
            mec, (long)Nc * 8 * 256, wx, eo, (long)Nc * 256, flag);

        // x1 ch0..2 (both relations): z=r*3+k, zdiv=3
        mgemm<128, 64, 1, 1><<<dim3(4, Nc / 128, 6), blk, 0, stream>>>(
            raw, 2, n0 * 256, 12582912, 4194304, 256,
            MfT, 0, 393216, 131072,
            x1, 0, (long)Nc * 2560, 512, 2560,
            b1, 0, 0, 512, nullptr, 256, 3, flag);
        // x1 ch3 = eo[r] @ W1c3T^T + b1[3]: z=r, zdiv=1
        mgemm<128, 64, 1, 1><<<dim3(4, Nc / 128, 2), blk, 0, stream>>>(
            eo, 0, 0, (long)Nc * 256, 0, 256,
            W1c3T, 0, 0, 0,
            x1, 3L * 512, (long)Nc * 2560, 0, 2560,
            b1, 3L * 512, 0, 0, nullptr, 256, 1, flag);
        // x1 ch4 = lbl[r,chunk] @ MlT[r]^T + b1[4]: z=r, zdiv=1
        mgemm<128, 64, 1, 1><<<dim3(4, Nc / 128, 2), blk, 0, stream>>>(
            lbl, 2, n0 * 64, 1048576, 0, 64,
            MlT, 0, 32768, 0,
            x1, 4L * 512, (long)Nc * 2560, 0, 2560,
            b1, 4L * 512, 0, 0, nullptr, 64, 1, flag);

        // LN1 + PReLU in place, both relations (2*Nc rows)
        ln1_k<<<2 * Nc, blk, 0, stream>>>(x1, g1, be1, a1, flag);

        // x2[r][:,ch,:] = x1[r][:,ch,:] @ W2T[ch]^T + b2[ch]: z=r*5+ch, zdiv=5
        mgemm<128, 64, 1, 1><<<dim3(4, Nc / 128, 10), blk, 0, stream>>>(
            x1, 1, 0, (long)Nc * 2560, 512, 2560,
            W2T, 0, 0, 262144,
            x2, 0, (long)Nc * 2560, 512, 2560,
            b2, 0, 0, 512, nullptr, 512, 5, flag);

        // LN2 + PReLU + channel pool -> hbc [Nc][2][512]
        ln2_pool_k<<<dim3(Nc, 2), blk, 0, stream>>>(
            x2, (long)Nc * 2560, g2, be2, a2, wr, hbc, flag);

        // global pool over R -> fin [Nc][512] (aliases x2, now dead)
        gpool_k<<<Nc, blk, 0, stream>>>(hbc, wg, fin, flag);

        // z = PReLU(fin @ Wf1T^T + bf1)
        mgemm<128, 64, 2, 1><<<dim3(4, Nc / 128, 1), blk, 0, stream>>>(
            fin, 1, 0, 0, 0, 512,
            Wf1T, 0, 0, 0,
            zb, 0, 0, 0, 512,
            bf1, 0, 0, 0, af, 512, 1, flag);
        // out = z @ Wf2T^T + bf2
        mgemm<64, 32, 1, 2><<<dim3(1, Nc / 128, 1), blk, 0, stream>>>(
            zb, 1, 0, 0, 0, 512,
            Wf2T, 0, 0, 0,
            d_out, n0 * 64, 0, 0, 64,
            bf2b, 0, 0, 0, nullptr, 512, 1, flag);
    }
}

// Round 4
// 948.739 us; speedup vs baseline: 1.0880x; 1.0880x over previous
//
#include <hip/hip_runtime.h>

// ---------------------------------------------------------------------------
// GlobalMetaAggregator  R=2,K=3,N=16384,V=256,E=1,L=8,VE=128,LK=1,OUT=64,
// IN=256,HID=512,C=5.
// Round 9: traffic-cutting fusions (K-loop tuning proven neutral 3 rounds).
//  (a) egp_k: extra GEMM + L=8 sigmoid-softmax pool fused -> writes eo
//      directly; mec intermediate (134MB W + 134MB R) eliminated.
//  (b) ln1 split: ln1_stats_k computes row (mu,rstd) only; LN1 affine+PReLU
//      applied inside x2 GEMM A-staging (LNA template path). ln1's 168MB
//      write eliminated.
// ---------------------------------------------------------------------------

typedef unsigned short bf16_t;
using ushort8v = __attribute__((ext_vector_type(8))) unsigned short;
using bf16x8   = __attribute__((ext_vector_type(8))) __bf16;
using f32x4    = __attribute__((ext_vector_type(4))) float;

#define WAITV(N) asm volatile("s_waitcnt vmcnt(%0)" :: "n"(N) : "memory")
#define WAITL0() asm volatile("s_waitcnt lgkmcnt(0)" ::: "memory")

__device__ __forceinline__ float bf2f(bf16_t u) {
    return __uint_as_float(((unsigned int)u) << 16);
}
__device__ __forceinline__ bf16_t f2bf(float f) {
    unsigned int u = __float_as_uint(f);
    u += 0x7FFFu + ((u >> 16) & 1u);   // RNE
    return (bf16_t)(u >> 16);
}
__device__ __forceinline__ float ld1(const void* p, long i, int dt) {
    return dt ? bf2f(((const bf16_t*)p)[i]) : ((const float*)p)[i];
}
__device__ __forceinline__ float4 ld4(const void* p, long i, int dt) {
    if (dt) {
        ushort4 v = *(const ushort4*)((const bf16_t*)p + i);
        return make_float4(bf2f(v.x), bf2f(v.y), bf2f(v.z), bf2f(v.w));
    }
    return *(const float4*)((const float*)p + i);
}
__device__ __forceinline__ ushort8v ld8bf(const void* p, long i, int dt) {
    if (dt) return *(const ushort8v*)((const bf16_t*)p + i);
    const float* f = (const float*)p + i;
    float4 a = *(const float4*)f, b = *(const float4*)(f + 4);
    ushort8v r;
    r[0] = f2bf(a.x); r[1] = f2bf(a.y); r[2] = f2bf(a.z); r[3] = f2bf(a.w);
    r[4] = f2bf(b.x); r[5] = f2bf(b.y); r[6] = f2bf(b.z); r[7] = f2bf(b.w);
    return r;
}
__device__ __forceinline__ float decode_scalar(const void* p, int isbf) {
    if (!isbf) return *(const float*)p;
    unsigned int u = *(const unsigned int*)p;
    if ((u & 0xFFFFu) == 0u) return __uint_as_float(u);
    return bf2f((bf16_t)(u & 0xFFFFu));
}
__device__ __forceinline__ float wave_reduce(float v) {
#pragma unroll
    for (int o = 32; o > 0; o >>= 1) v += __shfl_down(v, o, 64);
    return v;
}
// direct global -> LDS copy, 16 bytes per lane. LDS dest must be
// wave-uniform; hardware writes lane l's data at ldsbase + l*16.
__device__ __forceinline__ void gl_lds16(const void* g, void* l) {
    __builtin_amdgcn_global_load_lds(
        (const __attribute__((address_space(1))) void*)g,
        (__attribute__((address_space(3))) void*)l, 16, 0, 0);
}

// ---------------------------------------------------------------------------
__global__ void detect_k(const unsigned int* __restrict__ w, long nwords,
                         int* __restrict__ flag)
{
    const int lane = threadIdx.x;
    long idx = (long)lane * 997 + 13;
    if (idx >= nwords) idx = lane % (nwords > 0 ? nwords : 1);
    unsigned int word = w[idx];
    int e = (word >> 7) & 0xFF;
    int vote = (e >= 110 && e <= 134) ? 1 : 0;
    unsigned long long m = __ballot(vote);
    if (lane == 0) *flag = (__popcll(m) >= 32) ? 1 : 0;
}

// ---------------------------------------------------------------------------
// transpose: in [K][N] (flag dtype) -> out [N][K] bf16, batched over z
// ---------------------------------------------------------------------------
__global__ __launch_bounds__(256) void transT_k(
    const void* __restrict__ in, long inoff, long sInZ, int Kd, int Nd,
    bf16_t* __restrict__ out, long outoff, long sOutZ,
    const int* __restrict__ flag)
{
    const int isbf = *flag;
    const long z = blockIdx.z;
    long idx = (long)blockIdx.x * 256 + threadIdx.x;
    if (idx >= (long)Kd * Nd) return;
    int k = (int)(idx / Nd), n = (int)(idx % Nd);
    out[outoff + z * sOutZ + (long)n * Kd + k] =
        f2bf(ld1(in, inoff + z * sInZ + idx, isbf));
}

// ---------------------------------------------------------------------------
// fold GEMM (small): CT = (A@B)^T bf16.  A [M][K], B [K][N] flag dtype.
// ---------------------------------------------------------------------------
__global__ __launch_bounds__(256) void fold_gemmT_k(
    const void* __restrict__ A, long aoff, long sAz, int lda,
    const void* __restrict__ B, long boff, long sBz, int ldb,
    bf16_t* __restrict__ CT, long coff, long sCz, int ldcT,
    int K, const int* __restrict__ flag)
{
    const int isbf = *flag;
    __shared__ __align__(16) float As[16][68];
    __shared__ __align__(16) float Bs[16][68];
    const int z = blockIdx.z, t = threadIdx.x;
    const int tx = t & 15, ty = t >> 4;
    const int am = t >> 2, ak = (t & 3) << 2;
    const int bn = tx << 2;
    const long aBase = aoff + z * sAz + (long)(blockIdx.y * 64 + am) * lda + ak;
    const long bBase = boff + z * sBz + (long)ty * ldb + blockIdx.x * 64 + bn;
    float acc[4][4] = {};
    for (int k0 = 0; k0 < K; k0 += 16) {
        float4 av = ld4(A, aBase + k0, isbf);
        float4 bv = ld4(B, bBase + (long)k0 * ldb, isbf);
        __syncthreads();
        As[ak + 0][am] = av.x; As[ak + 1][am] = av.y;
        As[ak + 2][am] = av.z; As[ak + 3][am] = av.w;
        *(float4*)&Bs[ty][bn] = bv;
        __syncthreads();
#pragma unroll
        for (int k = 0; k < 16; k++) {
            float4 a4 = *(const float4*)&As[k][ty << 2];
            float4 b4 = *(const float4*)&Bs[k][tx << 2];
            float ar[4] = {a4.x, a4.y, a4.z, a4.w};
            float br[4] = {b4.x, b4.y, b4.z, b4.w};
#pragma unroll
            for (int i = 0; i < 4; i++)
#pragma unroll
                for (int j = 0; j < 4; j++) acc[i][j] += ar[i] * br[j];
        }
    }
    const int cm = blockIdx.y * 64 + (ty << 2);
    const int cn = blockIdx.x * 64 + (tx << 2);
#pragma unroll
    for (int i = 0; i < 4; i++)
#pragma unroll
        for (int j = 0; j < 4; j++)
            CT[coff + z * sCz + (long)(cn + j) * ldcT + (cm + i)] = f2bf(acc[i][j]);
}

// ---------------------------------------------------------------------------
// MFMA GEMM: C[z] = A[z] @ BT[z]^T (+bias)(+PReLU), f32 accumulate.
// Per-z offsets: with zq=z/zdiv, zr=z%zdiv, offset = off + zq*s1 + zr*s2.
// A [M][K] (adt 0=f32,1=bf16,2=flag), BT [N][K] bf16.
// Tile 128 x BN_, BK=32, 4 waves (2x2), wave tile 64 x WNW_.
// MODE: 0 none, 1 +bias, 2 +bias+PReLU.  CD: 1 bf16 out, 2 flag-dtype out.
// LNA: A-staging applies LayerNorm affine + PReLU using per-row (mu,rstd)
// from lnstats (rows indexed zq*Ntot+row), cols zr*sA2 + k (x2-specific).
// Counted-vmcnt pipeline: 3 LDS buffers, depth-2 prefetch, 1 barrier/step.
// ---------------------------------------------------------------------------
template <int BN_, int WNW_, int MODE, int CD, int LNA>
__global__ __launch_bounds__(256) void mgemm(
    const void* __restrict__ A, int adt, long aoff, long sA1, long sA2, int lda,
    const bf16_t* __restrict__ BT, long boff, long sB1, long sB2,
    void* __restrict__ C, long coff, long sC1, long sC2, int ldc,
    const void* __restrict__ bias, long biasoff, long sBi1, long sBi2,
    const void* __restrict__ alpha_ptr, int K, int zdiv,
    const void* __restrict__ lnstats, const void* __restrict__ lng,
    const void* __restrict__ lnbe, const void* __restrict__ lnal,
    const int* __restrict__ flag)
{
    constexpr int NJ = WNW_ / 16;
    constexpr int BROUNDS = BN_ / 64;   // 256 lanes * 16B = 64 rows per round
    const int isbf = *flag;
    const int adt_ = (adt == 2) ? isbf : adt;
    const int cdt = (CD == 2) ? isbf : 1;

    __shared__ __align__(16) unsigned short As[3][128 * 32];
    __shared__ __align__(16) unsigned short Bs[3][BN_ * 32];

    const int t = threadIdx.x;
    const int lane = t & 63, w = t >> 6;
    const int quad = lane >> 4, r16 = lane & 15;
    const int wy = w >> 1, wx = w & 1;
    const int z = blockIdx.z;
    const int zq = z / zdiv, zr = z % zdiv;
    const long blockM = (long)blockIdx.y * 128;
    const int  blockN = blockIdx.x * BN_;

    f32x4 acc[4][NJ];
    const f32x4 zero4 = {0.f, 0.f, 0.f, 0.f};
#pragma unroll
    for (int i = 0; i < 4; i++)
#pragma unroll
        for (int j = 0; j < NJ; j++) acc[i][j] = zero4;

    const long aBase = aoff + zq * sA1 + zr * sA2;
    const long bBase = boff + zq * sB1 + zr * sB2;

    const bool fastA = (adt_ == 1) && !LNA;
    const bf16_t* Abf = (const bf16_t*)A;

    // hoisted LN per-thread row stats (rows t>>2 and 64+(t>>2) of the M-tile)
    float mu0 = 0.f, rs0 = 0.f, mu1 = 0.f, rs1 = 0.f, lnalpha = 0.f;
    if (LNA) {
        const float* st = (const float*)lnstats;
        const long Ntot = (long)gridDim.y * 128;
        const long r0 = zq * Ntot + blockM + (t >> 2);
        mu0 = st[r0 * 2];        rs0 = st[r0 * 2 + 1];
        mu1 = st[(r0 + 64) * 2]; rs1 = st[(r0 + 64) * 2 + 1];
        lnalpha = decode_scalar(lnal, isbf);
    }

    // stage one BK=32 K-tile into buffer `buf`
    auto STAGE = [&](int buf, int ti) {
        const int k0 = ti << 5;
        if (fastA) {
#pragma unroll
            for (int c = 0; c < 2; c++) {
                const int lin = c * 256 + t;             // lin = m*4 + k8
                const int m = lin >> 2, kq = (lin & 3) * 8;
                gl_lds16(Abf + aBase + (blockM + m) * (long)lda + k0 + kq,
                         &As[buf][(size_t)(c * 256 + w * 64) * 8]);
            }
        } else {
            ushort8v av[2];
#pragma unroll
            for (int c = 0; c < 2; c++) {
                const int lin = c * 256 + t;
                const int m = lin >> 2, kq = (lin & 3) * 8;
                if (LNA) {
                    // x1 bf16 load + LN1 affine + PReLU
                    ushort8v x = *(const ushort8v*)(
                        Abf + aBase + (blockM + m) * (long)lda + k0 + kq);
                    const long kc = (long)zr * sA2 + k0 + kq;  // global col
                    float4 ga = ld4(lng,  kc,     isbf);
                    float4 gb = ld4(lng,  kc + 4, isbf);
                    float4 ba = ld4(lnbe, kc,     isbf);
                    float4 bb = ld4(lnbe, kc + 4, isbf);
                    const float mu = c ? mu1 : mu0, rs = c ? rs1 : rs0;
                    float gr[8] = {ga.x, ga.y, ga.z, ga.w, gb.x, gb.y, gb.z, gb.w};
                    float br[8] = {ba.x, ba.y, ba.z, ba.w, bb.x, bb.y, bb.z, bb.w};
                    ushort8v o;
#pragma unroll
                    for (int e = 0; e < 8; e++) {
                        float y = (bf2f(x[e]) - mu) * rs;
                        y = y * gr[e] + br[e];
                        y = (y >= 0.f) ? y : lnalpha * y;
                        o[e] = f2bf(y);
                    }
                    av[c] = o;
                } else {
                    av[c] = ld8bf(A, aBase + (blockM + m) * (long)lda + k0 + kq, 0);
                }
            }
#pragma unroll
            for (int c = 0; c < 2; c++)
                *(ushort8v*)&As[buf][(size_t)(c * 256 + t) * 8] = av[c];
        }
#pragma unroll
        for (int c = 0; c < BROUNDS; c++) {
            const int lin = c * 256 + t;
            const int n = lin >> 2, kq = (lin & 3) * 8;
            gl_lds16(BT + bBase + (long)(blockN + n) * K + k0 + kq,
                     &Bs[buf][(size_t)(c * 256 + w * 64) * 8]);
        }
    };

    const int nt = K >> 5;
    STAGE(0, 0);
    if (nt > 1) STAGE(1, 1);

    int cur = 0;
    for (int ti = 0; ti < nt; ++ti) {
        // WAR safety: my ds_reads (and any staged ds_writes) complete
        WAITL0();
        // tile ti landed; tile ti+1 (if staged) may remain in flight
        if (fastA) {
            if (ti + 1 < nt) WAITV(2 + BROUNDS); else WAITV(0);
        } else {
            if (ti + 1 < nt) WAITV(BROUNDS);     else WAITV(0);
        }
        __builtin_amdgcn_s_barrier();
        __builtin_amdgcn_sched_barrier(0);

        // depth-2 prefetch into the buffer last read at iter ti-1
        if (ti + 2 < nt) {
            int sb = cur + 2; if (sb >= 3) sb -= 3;
            STAGE(sb, ti + 2);
        }

        bf16x8 af[4], bfr[NJ];
#pragma unroll
        for (int i = 0; i < 4; i++) {
            int m = wy * 64 + i * 16 + r16;
            af[i] = __builtin_bit_cast(bf16x8,
                        *(const ushort8v*)&As[cur][m * 32 + quad * 8]);
        }
#pragma unroll
        for (int j = 0; j < NJ; j++) {
            int n = wx * WNW_ + j * 16 + r16;
            bfr[j] = __builtin_bit_cast(bf16x8,
                        *(const ushort8v*)&Bs[cur][n * 32 + quad * 8]);
        }
#pragma unroll
        for (int i = 0; i < 4; i++)
#pragma unroll
            for (int j = 0; j < NJ; j++)
                acc[i][j] = __builtin_amdgcn_mfma_f32_16x16x32_bf16(
                    af[i], bfr[j], acc[i][j], 0, 0, 0);

        cur = (cur == 2) ? 0 : cur + 1;
    }

    const float alpha = (MODE == 2) ? decode_scalar(alpha_ptr, isbf) : 0.f;
    const long cBase = coff + zq * sC1 + zr * sC2;
#pragma unroll
    for (int j = 0; j < NJ; j++) {
        const int n = blockN + wx * WNW_ + j * 16 + r16;
        const float bz = (MODE >= 1)
            ? ld1(bias, biasoff + zq * sBi1 + zr * sBi2 + n, isbf) : 0.f;
#pragma unroll
        for (int i = 0; i < 4; i++) {
            const long m0 = blockM + wy * 64 + i * 16 + quad * 4;
#pragma unroll
            for (int rg = 0; rg < 4; rg++) {
                float v = acc[i][j][rg] + bz;
                if (MODE == 2) v = (v >= 0.f) ? v : alpha * v;
                const long off = cBase + (m0 + rg) * (long)ldc + n;
                if (cdt) ((bf16_t*)C)[off] = f2bf(v);
                else     ((float*)C)[off] = v;
            }
        }
    }
}

// ---------------------------------------------------------------------------
// egp_k: fused extra GEMM + L=8 sigmoid-softmax pool.
// Per block: 8 nodes (64 M-rows = node*8+l), full N=256 cols, K=128.
// 4 waves 1x4 (wave tile 64M x 64N, NJ=4).  A = extra (flag dtype, lda=128),
// B = eT bf16 [256][128].  Epilogue pools over l in-register -> EO f32.
// ---------------------------------------------------------------------------
__global__ __launch_bounds__(256) void egp_k(
    const void* __restrict__ extra, long aoff, long sEz,
    const bf16_t* __restrict__ eT, long sBz,
    const void* __restrict__ wxp,
    float* __restrict__ EO, long sEOz,
    const int* __restrict__ flag)
{
    const int isbf = *flag;
    __shared__ __align__(16) unsigned short As2[64 * 32];
    __shared__ __align__(16) unsigned short Bs2[256 * 32];
    __shared__ float dotl[64][4];
    __shared__ float el[64];
    __shared__ float gwl[64];

    const int t = threadIdx.x;
    const int lane = t & 63, w = t >> 6;
    const int quad = lane >> 4, r16 = lane & 15;
    const long rowBase = (long)blockIdx.y * 64;
    const int z = blockIdx.z;

    f32x4 acc[4][4];
    const f32x4 zero4 = {0.f, 0.f, 0.f, 0.f};
#pragma unroll
    for (int i = 0; i < 4; i++)
#pragma unroll
        for (int j = 0; j < 4; j++) acc[i][j] = zero4;

    const long aBase = aoff + (long)z * sEz;
    const long bBase = (long)z * sBz;

    for (int k0 = 0; k0 < 128; k0 += 32) {
        // A tile [64][32]: global->reg (one ushort8 per thread)
        ushort8v av = ld8bf(extra,
            aBase + (rowBase + (t >> 2)) * 128 + k0 + (t & 3) * 8, isbf);
        __syncthreads();                 // prev-iter LDS reads done
        *(ushort8v*)&As2[t * 8] = av;
        // B tile [256][32] via global_load_lds
#pragma unroll
        for (int c = 0; c < 4; c++) {
            const int lin = c * 256 + t;
            const int n = lin >> 2, kq = (lin & 3) * 8;
            gl_lds16(eT + bBase + (long)n * 128 + k0 + kq,
                     &Bs2[(size_t)(c * 256 + w * 64) * 8]);
        }
        __syncthreads();                 // drains vmcnt+lgkm

        bf16x8 af[4], bfr[4];
#pragma unroll
        for (int i = 0; i < 4; i++) {
            int m = i * 16 + r16;
            af[i] = __builtin_bit_cast(bf16x8,
                        *(const ushort8v*)&As2[m * 32 + quad * 8]);
        }
#pragma unroll
        for (int j = 0; j < 4; j++) {
            int n = w * 64 + j * 16 + r16;
            bfr[j] = __builtin_bit_cast(bf16x8,
                        *(const ushort8v*)&Bs2[n * 32 + quad * 8]);
        }
#pragma unroll
        for (int i = 0; i < 4; i++)
#pragma unroll
            for (int j = 0; j < 4; j++)
                acc[i][j] = __builtin_amdgcn_mfma_f32_16x16x32_bf16(
                    af[i], bfr[j], acc[i][j], 0, 0, 0);
    }

    // ---- epilogue: per-row dot with w, sigmoid-softmax over l=8, pool ----
    float wv[4];
#pragma unroll
    for (int j = 0; j < 4; j++) wv[j] = ld1(wxp, w * 64 + j * 16 + r16, isbf);

#pragma unroll
    for (int i = 0; i < 4; i++) {
#pragma unroll
        for (int rg = 0; rg < 4; rg++) {
            float d = acc[i][0][rg] * wv[0] + acc[i][1][rg] * wv[1]
                    + acc[i][2][rg] * wv[2] + acc[i][3][rg] * wv[3];
            d += __shfl_xor(d, 1, 64);
            d += __shfl_xor(d, 2, 64);
            d += __shfl_xor(d, 4, 64);
            d += __shfl_xor(d, 8, 64);
            if (r16 == 0) dotl[i * 16 + quad * 4 + rg][w] = d;
        }
    }
    __syncthreads();
    if (t < 64) {
        float s = dotl[t][0] + dotl[t][1] + dotl[t][2] + dotl[t][3];
        float sg = 1.f / (1.f + expf(-s));
        el[t] = expf(sg);
    }
    __syncthreads();
    if (t < 64) {
        const int nb = t & ~7;
        float S = 0.f;
#pragma unroll
        for (int l = 0; l < 8; l++) S += el[nb + l];
        gwl[t] = el[t] / S;
    }
    __syncthreads();

#pragma unroll
    for (int i = 0; i < 4; i++) {
        const int node = i * 2 + (quad >> 1);
        float gw[4];
#pragma unroll
        for (int rg = 0; rg < 4; rg++) gw[rg] = gwl[i * 16 + quad * 4 + rg];
#pragma unroll
        for (int j = 0; j < 4; j++) {
            float ts = gw[0] * acc[i][j][0] + gw[1] * acc[i][j][1]
                     + gw[2] * acc[i][j][2] + gw[3] * acc[i][j][3];
            ts += __shfl_xor(ts, 16, 64);
            if ((quad & 1) == 0) {
                const long ng = (long)blockIdx.y * 8 + node;
                EO[(long)z * sEOz + ng * 256 + w * 64 + j * 16 + r16] = ts;
            }
        }
    }
}

// ---------------------------------------------------------------------------
// ln1_stats_k: per-row mean/rstd over 2560 bf16; grid = #rows, 256 thr.
// ---------------------------------------------------------------------------
__global__ __launch_bounds__(256) void ln1_stats_k(
    const bf16_t* __restrict__ X, float* __restrict__ st)
{
    const int n = blockIdx.x, t = threadIdx.x;
    const bf16_t* row = X + (long)n * 2560;
    float s = 0.f, q = 0.f;
    ushort8v a = *(const ushort8v*)(row + t * 8);
#pragma unroll
    for (int e = 0; e < 8; e++) { float f = bf2f(a[e]); s += f; q += f * f; }
    if (t < 64) {
        ushort8v b = *(const ushort8v*)(row + 2048 + t * 8);
#pragma unroll
        for (int e = 0; e < 8; e++) { float f = bf2f(b[e]); s += f; q += f * f; }
    }
    __shared__ float redS[4], redQ[4];
    const int lane = t & 63, wid = t >> 6;
    float ws_ = wave_reduce(s), wq = wave_reduce(q);
    if (lane == 0) { redS[wid] = ws_; redQ[wid] = wq; }
    __syncthreads();
    if (t == 0) {
        const float S = redS[0] + redS[1] + redS[2] + redS[3];
        const float Q = redQ[0] + redQ[1] + redQ[2] + redQ[3];
        const float mean = S * (1.f / 2560.f);
        const float rstd =
            rsqrtf(fmaxf(Q * (1.f / 2560.f) - mean * mean, 0.f) + 1e-5f);
        st[(long)n * 2]     = mean;
        st[(long)n * 2 + 1] = rstd;
    }
}

// ---------------------------------------------------------------------------
// LN2 + PReLU + channel pool (C=5) -> H[n*1024 + r*512 + :] bf16
// grid (Nc, 2): blockIdx.y = relation
// ---------------------------------------------------------------------------
__global__ __launch_bounds__(256) void ln2_pool_k(
    const bf16_t* __restrict__ X, long sXz, const void* __restrict__ g,
    const void* __restrict__ be, const void* __restrict__ alpha_ptr,
    const void* __restrict__ wr,
    bf16_t* __restrict__ H, const int* __restrict__ flag)
{
    const int isbf = *flag;
    const int n = blockIdx.x, t = threadIdx.x, rr = blockIdx.y;
    const bf16_t* row = X + rr * sXz + (long)n * 2560;
    float v[5][2], s = 0.f, sq = 0.f;
#pragma unroll
    for (int c = 0; c < 5; c++)
#pragma unroll
        for (int hi = 0; hi < 2; hi++) {
            float x = bf2f(row[c * 512 + hi * 256 + t]);
            v[c][hi] = x; s += x; sq += x * x;
        }
    __shared__ float redS[4], redQ[4];
    const int lane = t & 63, wid = t >> 6;
    float ws_ = wave_reduce(s), wq = wave_reduce(sq);
    if (lane == 0) { redS[wid] = ws_; redQ[wid] = wq; }
    __syncthreads();
    const float S = redS[0] + redS[1] + redS[2] + redS[3];
    const float Q = redQ[0] + redQ[1] + redQ[2] + redQ[3];
    const float mean = S * (1.f / 2560.f);
    const float rstd = rsqrtf(fmaxf(Q * (1.f / 2560.f) - mean * mean, 0.f) + 1e-5f);
    const float alpha = decode_scalar(alpha_ptr, isbf);
    const float w0 = ld1(wr, (long)rr * 512 + t, isbf);
    const float w1 = ld1(wr, (long)rr * 512 + t + 256, isbf);
    float p[5];
#pragma unroll
    for (int c = 0; c < 5; c++) {
        p[c] = 0.f;
#pragma unroll
        for (int hi = 0; hi < 2; hi++) {
            int e = c * 512 + hi * 256 + t;
            float y = (v[c][hi] - mean) * rstd * ld1(g, e, isbf) + ld1(be, e, isbf);
            y = (y >= 0.f) ? y : alpha * y;
            v[c][hi] = y;
            p[c] += y * (hi ? w1 : w0);
        }
    }
    __shared__ float redP[5][4];
#pragma unroll
    for (int c = 0; c < 5; c++) {
        float pr = wave_reduce(p[c]);
        if (lane == 0) redP[c][wid] = pr;
    }
    __syncthreads();
    float gv[5], ssum = 0.f;
#pragma unroll
    for (int c = 0; c < 5; c++) {
        float sc = redP[c][0] + redP[c][1] + redP[c][2] + redP[c][3];
        float sg = 1.f / (1.f + expf(-sc));
        float e = expf(sg);
        gv[c] = e; ssum += e;
    }
    const float inv = 1.f / ssum;
#pragma unroll
    for (int hi = 0; hi < 2; hi++) {
        float o = 0.f;
#pragma unroll
        for (int c = 0; c < 5; c++) o += gv[c] * inv * v[c][hi];
        H[(long)n * 1024 + rr * 512 + hi * 256 + t] = f2bf(o);
    }
}

// ---------------------------------------------------------------------------
// global pool over R=2: H[Nc,2,512] -> F[Nc,512] bf16
// ---------------------------------------------------------------------------
__global__ __launch_bounds__(256) void gpool_k(
    const bf16_t* __restrict__ H, const void* __restrict__ wg,
    bf16_t* __restrict__ F, const int* __restrict__ flag)
{
    const int isbf = *flag;
    const int n = blockIdx.x, t = threadIdx.x;
    const bf16_t* base = H + (long)n * 1024;
    const float w0 = ld1(wg, t, isbf), w1 = ld1(wg, t + 256, isbf);
    float v[2][2], p[2];
#pragma unroll
    for (int r = 0; r < 2; r++) {
        v[r][0] = bf2f(base[r * 512 + t]);
        v[r][1] = bf2f(base[r * 512 + 256 + t]);
        p[r] = v[r][0] * w0 + v[r][1] * w1;
    }
    __shared__ float red[2][4];
    const int lane = t & 63, wid = t >> 6;
#pragma unroll
    for (int r = 0; r < 2; r++) {
        float pr = wave_reduce(p[r]);
        if (lane == 0) red[r][wid] = pr;
    }
    __syncthreads();
    float gv[2], ssum = 0.f;
#pragma unroll
    for (int r = 0; r < 2; r++) {
        float sc = red[r][0] + red[r][1] + red[r][2] + red[r][3];
        float sg = 1.f / (1.f + expf(-sc));
        float e = expf(sg);
        gv[r] = e; ssum += e;
    }
    const float inv = 1.f / ssum;
#pragma unroll
    for (int hi = 0; hi < 2; hi++) {
        F[(long)n * 512 + hi * 256 + t] =
            f2bf((gv[0] * v[0][hi] + gv[1] * v[1][hi]) * inv);
    }
}

// ---------------------------------------------------------------------------
extern "C" void kernel_launch(void* const* d_in, const int* in_sizes, int n_in,
                              void* d_out, int out_size, void* d_ws, size_t ws_size,
                              hipStream_t stream)
{
    const void* raw   = d_in[0];   // (2,3,16384,256)
    const void* extra = d_in[1];   // (2,1,16384,8,128)
    const void* lbl   = d_in[2];   // (2,1,16384,64)
    const void* femb  = d_in[3];   // (2,3,256,256)
    const void* eemb  = d_in[4];   // (2,1,128,256)
    const void* lemb  = d_in[5];   // (2,1,64,256)
    const void* wx    = d_in[6];   // (1,256)
    const void* wr    = d_in[7];   // (2,512)
    const void* wg    = d_in[8];   // (512,)
    const void* W1    = d_in[9];   // (5,256,512)
    const void* b1    = d_in[10];  // (5,512)
    const void* g1    = d_in[11];
    const void* be1   = d_in[12];
    const void* a1    = d_in[13];
    const void* W2    = d_in[14];  // (5,512,512)
    const void* b2    = d_in[15];
    const void* g2    = d_in[16];
    const void* be2   = d_in[17];
    const void* a2    = d_in[18];
    const void* Wf1   = d_in[19];  // (512,512)
    const void* bf1   = d_in[20];
    const void* af    = d_in[21];
    const void* Wf2   = d_in[22];  // (512,64)
    const void* bf2b  = d_in[23];

    // ---- workspace: flag | transposed bf16 weights | arena ----
    int*    flag  = (int*)d_ws;
    bf16_t* MfT   = (bf16_t*)((char*)d_ws + 256);  // [2][3][512][256]
    bf16_t* MlT   = MfT + 786432;                  // [2][512][64]
    bf16_t* W1c3T = MlT + 65536;                   // [512][256]
    bf16_t* W2T   = W1c3T + 131072;                // [5][512][512]
    bf16_t* Wf1T  = W2T + 1310720;                 // [512][512]
    bf16_t* Wf2T  = Wf1T + 262144;                 // [64][512]
    bf16_t* eT    = Wf2T + 32768;                  // [2][256][128]
    char*   arena = (char*)(eT + 65536);
    const size_t fixedBytes = 256 + 2654208 * 2;

    // per-node arena bytes: x1 2*5120 + x2 2*5120 + eo 2*1024 + hbc 2048
    // + stats 16
    int Nc = 16384;
    while (Nc > 128 && fixedBytes + (size_t)Nc * 24592 > ws_size) Nc >>= 1;
    const int NCH = 16384 / Nc;

    bf16_t* x1    = (bf16_t*)arena;                         // [2][Nc][2560]
    bf16_t* x2    = (bf16_t*)(arena + (size_t)Nc * 10240);  // [2][Nc][2560]
    float*  eo    = (float*) (arena + (size_t)Nc * 20480);  // [2][Nc][256] f32
    bf16_t* hbc   = (bf16_t*)(arena + (size_t)Nc * 22528);  // [Nc][2][512]
    float*  stats = (float*) (arena + (size_t)Nc * 24576);  // [2][Nc][2] f32
    bf16_t* fin = x2;                                       // [Nc][512] alias
    bf16_t* zb  = x2 + (size_t)Nc * 512;                    // [Nc][512] alias

    dim3 blk(256);

    detect_k<<<1, 64, 0, stream>>>((const unsigned int*)raw,
                                   (long)in_sizes[0] / 2, flag);

    // ---- weight transposes (bf16 [N][K]) ----
    transT_k<<<dim3(1024, 1, 5), blk, 0, stream>>>(W2, 0, 262144, 512, 512,
                                                   W2T, 0, 262144, flag);
    transT_k<<<dim3(512, 1, 1), blk, 0, stream>>>(W1, 3L * 131072, 0, 256, 512,
                                                  W1c3T, 0, 0, flag);
    transT_k<<<dim3(1024, 1, 1), blk, 0, stream>>>(Wf1, 0, 0, 512, 512,
                                                   Wf1T, 0, 0, flag);
    transT_k<<<dim3(128, 1, 1), blk, 0, stream>>>(Wf2, 0, 0, 512, 64,
                                                  Wf2T, 0, 0, flag);
    transT_k<<<dim3(128, 1, 2), blk, 0, stream>>>(eemb, 0, 32768, 128, 256,
                                                  eT, 0, 32768, flag);

    // ---- folds: MfT[r,k] = (femb[r,k]@W1[k])^T, MlT[r] = (lemb[r]@W1[4])^T
    for (int r = 0; r < 2; r++) {
        fold_gemmT_k<<<dim3(8, 4, 3), blk, 0, stream>>>(
            femb, (long)r * 196608, 65536, 256,
            W1, 0, 131072, 512,
            MfT, (long)r * 393216, 131072, 256, 256, flag);
    }
    fold_gemmT_k<<<dim3(8, 1, 2), blk, 0, stream>>>(
        lemb, 0, 16384, 256,
        W1, 4L * 131072, 0, 512,
        MlT, 0, 32768, 64, 256, flag);

    for (int c = 0; c < NCH; c++) {
        const long n0 = (long)c * Nc;

        // fused extra GEMM + pool -> eo [2][Nc][256] f32 (mec eliminated)
        egp_k<<<dim3(1, Nc / 8, 2), blk, 0, stream>>>(
            extra, n0 * 1024, 16777216, eT, 32768, wx,
            eo, (long)Nc * 256, flag);

        // x1 ch0..2 (both relations): z=r*3+k, zdiv=3
        mgemm<128, 64, 1, 1, 0><<<dim3(4, Nc / 128, 6), blk, 0, stream>>>(
            raw, 2, n0 * 256, 12582912, 4194304, 256,
            MfT, 0, 393216, 131072,
            x1, 0, (long)Nc * 2560, 512, 2560,
            b1, 0, 0, 512, nullptr, 256, 3,
            nullptr, nullptr, nullptr, nullptr, flag);
        // x1 ch3 = eo[r] @ W1c3T^T + b1[3]: z=r, zdiv=1
        mgemm<128, 64, 1, 1, 0><<<dim3(4, Nc / 128, 2), blk, 0, stream>>>(
            eo, 0, 0, (long)Nc * 256, 0, 256,
            W1c3T, 0, 0, 0,
            x1, 3L * 512, (long)Nc * 2560, 0, 2560,
            b1, 3L * 512, 0, 0, nullptr, 256, 1,
            nullptr, nullptr, nullptr, nullptr, flag);
        // x1 ch4 = lbl[r,chunk] @ MlT[r]^T + b1[4]: z=r, zdiv=1
        mgemm<128, 64, 1, 1, 0><<<dim3(4, Nc / 128, 2), blk, 0, stream>>>(
            lbl, 2, n0 * 64, 1048576, 0, 64,
            MlT, 0, 32768, 0,
            x1, 4L * 512, (long)Nc * 2560, 0, 2560,
            b1, 4L * 512, 0, 0, nullptr, 64, 1,
            nullptr, nullptr, nullptr, nullptr, flag);

        // LN1 stats only (mu,rstd per row); apply is fused into x2 staging
        ln1_stats_k<<<2 * Nc, blk, 0, stream>>>(x1, stats);

        // x2[r][:,ch,:] = PReLU(LN1(x1))[r][:,ch,:] @ W2T[ch]^T + b2[ch]
        mgemm<128, 64, 1, 1, 1><<<dim3(4, Nc / 128, 10), blk, 0, stream>>>(
            x1, 1, 0, (long)Nc * 2560, 512, 2560,
            W2T, 0, 0, 262144,
            x2, 0, (long)Nc * 2560, 512, 2560,
            b2, 0, 0, 512, nullptr, 512, 5,
            stats, g1, be1, a1, flag);

        // LN2 + PReLU + channel pool -> hbc [Nc][2][512]
        ln2_pool_k<<<dim3(Nc, 2), blk, 0, stream>>>(
            x2, (long)Nc * 2560, g2, be2, a2, wr, hbc, flag);

        // global pool over R -> fin [Nc][512] (aliases x2, now dead)
        gpool_k<<<Nc, blk, 0, stream>>>(hbc, wg, fin, flag);

        // z = PReLU(fin @ Wf1T^T + bf1)
        mgemm<128, 64, 2, 1, 0><<<dim3(4, Nc / 128, 1), blk, 0, stream>>>(
            fin, 1, 0, 0, 0, 512,
            Wf1T, 0, 0, 0,
            zb, 0, 0, 0, 512,
            bf1, 0, 0, 0, af, 512, 1,
            nullptr, nullptr, nullptr, nullptr, flag);
        // out = z @ Wf2T^T + bf2
        mgemm<64, 32, 1, 2, 0><<<dim3(1, Nc / 128, 1), blk, 0, stream>>>(
            zb, 1, 0, 0, 0, 512,
            Wf2T, 0, 0, 0,
            d_out, n0 * 64, 0, 0, 64,
            bf2b, 0, 0, 0, nullptr, 512, 1,
            nullptr, nullptr, nullptr, nullptr, flag);
    }
}